// Round 4
// baseline (322.607 us; speedup 1.0000x reference)
//
#include <hip/hip_runtime.h>
#include <hip/hip_fp16.h>

#define NEG  (-1e30f)
#define LN2F 0.69314718056f

// Problem dims (fixed by setup_inputs): B=16, TXT=128, MEL=512, NM=80
#define B_   16
#define TXT_ 128
#define MEL_ 512
#define NM_  80
#define IT_  8     // i-rows per lp block

#define CH_   80                  // mel rows per LDS chunk (5 x 16 groups)
#define NCH_  7                   // ceil(512/80); last chunk = 32 rows
#define CHD_  (CH_ * 64)          // dwords per chunk buffer = 5120 (20 KB)

typedef float vf2 __attribute__((ext_vector_type(2)));

// ---------------------------------------------------------------------------
// Kernel 1: log_prob_matrix (proven since R3). Also zeroes out[0].
// ---------------------------------------------------------------------------
__global__ __launch_bounds__(512) void lp_kernel(
    const float* __restrict__ mu_logvar,  // (B, TXT, 2*NM)
    const float* __restrict__ melspec,    // (B, NM, MEL)
    float* __restrict__ lp_out,           // (B, TXT, MEL)  = d_out + 1
    float* __restrict__ out0)             // d_out[0]
{
    const int i0 = blockIdx.x * IT_;
    const int b  = blockIdx.y;
    const int t  = threadIdx.x;

    __shared__ float2 s_wb[IT_][NM_];
    __shared__ float  s_cp[IT_ * NM_];
    __shared__ float  s_cc[IT_];

    for (int u = t; u < IT_ * NM_; u += 512) {   // 640 > 512: strided loop!
        int ii = u / NM_;
        int n  = u - ii * NM_;
        const float* row = mu_logvar + (size_t)(b * TXT_ + i0 + ii) * (2 * NM_);
        float mu = row[n];
        float lv = row[NM_ + n];
        float w  = __expf(-lv);
        s_wb[ii][n] = make_float2(w, -2.f * mu * w);
        s_cp[u]     = mu * mu * w + lv;
    }
    __syncthreads();
    if (t < IT_) {
        float c = 0.f;
        #pragma unroll
        for (int n = 0; n < NM_; ++n) c += s_cp[t * NM_ + n];
        s_cc[t] = c;
    }
    __syncthreads();

    const float* xcol = melspec + (size_t)b * NM_ * MEL_ + t;
    float acc[IT_];
    #pragma unroll
    for (int ii = 0; ii < IT_; ++ii) acc[ii] = 0.f;

    #pragma unroll 4
    for (int n = 0; n < NM_; ++n) {
        float x  = xcol[(size_t)n * MEL_];
        float x2 = x * x;
        #pragma unroll
        for (int ii = 0; ii < IT_; ++ii) {
            float2 wb = s_wb[ii][n];
            acc[ii] = fmaf(wb.x, x2, fmaf(wb.y, x, acc[ii]));
        }
    }

    const size_t rowbase = ((size_t)(b * TXT_ + i0)) * MEL_ + t;
    #pragma unroll
    for (int ii = 0; ii < IT_; ++ii) {
        lp_out[rowbase + (size_t)ii * MEL_] =
            (-0.5f / (float)NM_) * (acc[ii] + s_cc[ii]);
    }

    if (i0 == 0 && b == 0 && t == 0) *out0 = 0.f;
}

// ---------------------------------------------------------------------------
// Kernel 2 (fused wt + scan), static shared (<64 KB), NO register stash.
// One block per b, 512 threads. Thread t owns mel column t.
//
// R3 post-mortem: stashing the f32 column in vv[128] VGPRs spilled to
// scratch (VGPR cap 128, WRITE_SIZE showed 2.4 MB of spill) -> 135 us.
// Fix: lp is 256 KB/block and L2-resident after Phase A, so WRITEW simply
// RE-READS the column from global (coalesced, L2-hit, overlapped with the
// scan). Phase A keeps only the running max.
//
// Pipeline (unchanged from R3, numerics-proven): 3-buffer chunks of CH=80
// mel rows (60 KB LDS). Iter c: wave0 scans chunk c from buf[c%3] while
// the threads owning chunk c+2 exp+pack+write buf[(c+2)%3]; one barrier
// per iter. LDS swizzle D(row,p) = row*64 + (p ^ (row&31)) keeps both the
// column-writes and the scan's row-reads <=2-way (free).
// Scan: R10 machinery — DPP shr1 + add/mul, exact power-of-2 renorm every
// <=16 steps (CH=80=5x16 aligned; 15-step prologue). fp16 only touches w
// (<=1/2, 2.4e-4 rel); the lp output tensor is untouched.
// ---------------------------------------------------------------------------
__device__ __forceinline__ float dpp_shr1_zero(float x) {
    int r = __builtin_amdgcn_update_dpp(
        0, __builtin_bit_cast(int, x), 0x138 /*wave_shr:1*/, 0xf, 0xf, false);
    return __builtin_bit_cast(float, r);
}

#define DPPMAX(M, CTRL, RM)                                               \
    do {                                                                  \
        int _t = __builtin_amdgcn_update_dpp(                             \
            __builtin_bit_cast(int, M), __builtin_bit_cast(int, M),       \
            CTRL, RM, 0xf, false);                                        \
        M = fmaxf(M, __builtin_bit_cast(float, _t));                      \
    } while (0)

__global__ __launch_bounds__(512) void fused_scan(
    const float* __restrict__ lp,          // (B, TXT, MEL) = d_out + 1
    const int* __restrict__ text_len, const int* __restrict__ mel_len,
    float* __restrict__ out0)
{
    __shared__ unsigned int wbuf[3 * CHD_];   // 60 KB
    __shared__ float wsum[8];
    __shared__ float s_lp00;

    const int b = blockIdx.x;
    const int t = threadIdx.x;                // mel column, 0..511
    const int l = t;                          // lane id when in wave 0
    const float* col = lp + (size_t)b * TXT_ * MEL_ + t;

    const int Tend = mel_len[b], TendM1 = Tend - 1;   // Tend in [256,512]

    // ---- Phase A: column max only (no stash -> no spill) ---------------
    float m = NEG;
    #pragma unroll 8
    for (int p = 0; p < TXT_; ++p) m = fmaxf(m, col[(size_t)p * MEL_]);
    const float mu_t = m + LN2F;

    float contrib = (t >= 1 && t <= TendM1) ? mu_t : 0.f;
    #pragma unroll
    for (int off = 32; off; off >>= 1) contrib += __shfl_down(contrib, off);
    if ((t & 63) == 0) wsum[t >> 6] = contrib;
    if (t == 0) s_lp00 = col[0];              // lp[b][0][0]

    const int myc  = t / CH_;                 // this thread's chunk
    const int rloc = t - myc * CH_;
    unsigned int* wb = wbuf + (myc % 3) * CHD_ + rloc * 64;
    const int swz = t & 31;

    #define WRITEW()                                                      \
        do {                                                              \
            _Pragma("unroll")                                             \
            for (int p = 0; p < 64; ++p) {                                \
                float f0 = col[(size_t)(2 * p)     * MEL_];               \
                float f1 = col[(size_t)(2 * p + 1) * MEL_];               \
                float e0 = __expf(f0 - mu_t);                             \
                float e1 = __expf(f1 - mu_t);                             \
                wb[p ^ swz] = __builtin_bit_cast(                         \
                    unsigned int, __floats2half2_rn(e0, e1));             \
            }                                                             \
        } while (0)

    if (myc <= 1) WRITEW();                   // chunks 0,1 pre-filled
    __syncthreads();

    // ---- Phase C state -------------------------------------------------
    float s0 = (l == 0) ? 1.f : 0.f;
    float s1 = 0.f;
    float fin0 = 0.f, fin1 = 0.f;
    int   shift_acc = 0, fsh = 0;
    vf2 A[16], Bq[16];

    #define LOADN(ARR, RL0, N)                                            \
        _Pragma("unroll")                                                 \
        for (int j = 0; j < (N); ++j) {                                   \
            int rl = (RL0) + j;                                           \
            unsigned int u_ = bb[rl * 64 + (l ^ ((lo + rl) & 31))];       \
            float2 f_ = __half22float2(__builtin_bit_cast(__half2, u_));  \
            ARR[j].x = f_.x; ARR[j].y = f_.y;                             \
        }

    #define STEPN(ARR, RL0, N)                                            \
        _Pragma("unroll")                                                 \
        for (int j = 0; j < (N); ++j) {                                   \
            int row = lo + (RL0) + j;                                     \
            float nb  = dpp_shr1_zero(s1);                                \
            float ns0 = (s0 + nb) * ARR[j].x;                             \
            float ns1 = (s1 + s0) * ARR[j].y;                             \
            bool hit = (row == TendM1);                                   \
            fin0 = hit ? ns0 : fin0;                                      \
            fin1 = hit ? ns1 : fin1;                                      \
            fsh  = hit ? shift_acc : fsh;                                 \
            s0 = ns0; s1 = ns1;                                           \
        }

    #define RENORM16()                                                    \
        do {                                                              \
            float mm = fmaxf(s0, s1);                                     \
            DPPMAX(mm, 0x111, 0xf);   /* row_shr:1  */                    \
            DPPMAX(mm, 0x112, 0xf);   /* row_shr:2  */                    \
            DPPMAX(mm, 0x114, 0xf);   /* row_shr:4  */                    \
            DPPMAX(mm, 0x118, 0xf);   /* row_shr:8  */                    \
            DPPMAX(mm, 0x142, 0xa);   /* row_bcast:15 -> rows 1,3 */      \
            DPPMAX(mm, 0x143, 0xc);   /* row_bcast:31 -> rows 2,3 */      \
            float M = __builtin_bit_cast(                                 \
                float, __builtin_amdgcn_readlane(                         \
                           __builtin_bit_cast(int, mm), 63));             \
            if (M > 0.f) {                                                \
                int e;                                                    \
                (void)frexpf(M, &e);                                      \
                float sc = ldexpf(1.f, -e);                               \
                s0 *= sc; s1 *= sc;                                       \
                shift_acc += e;                                           \
            }                                                             \
        } while (0)

    for (int c = 0; c < NCH_; ++c) {
        if (t < 64) {
            const unsigned int* bb = wbuf + (c % 3) * CHD_;
            const int lo = c * CH_;
            if (c == 0) {
                LOADN(A, 1, 15); LOADN(Bq, 16, 16);
                STEPN(A, 1, 15);  RENORM16();
                LOADN(A, 32, 16); STEPN(Bq, 16, 16); RENORM16();
                LOADN(Bq, 48, 16); STEPN(A, 32, 16); RENORM16();
                LOADN(A, 64, 16); STEPN(Bq, 48, 16); RENORM16();
                STEPN(A, 64, 16); RENORM16();
            } else if (c < 6) {
                LOADN(A, 0, 16); LOADN(Bq, 16, 16);
                STEPN(A, 0, 16);  RENORM16();
                LOADN(A, 32, 16); STEPN(Bq, 16, 16); RENORM16();
                LOADN(Bq, 48, 16); STEPN(A, 32, 16); RENORM16();
                LOADN(A, 64, 16); STEPN(Bq, 48, 16); RENORM16();
                STEPN(A, 64, 16); RENORM16();
            } else {                          // c == 6: rows 480..511
                LOADN(A, 0, 16); LOADN(Bq, 16, 16);
                STEPN(A, 0, 16);  RENORM16();
                STEPN(Bq, 16, 16); RENORM16();
            }
        } else if (myc == c + 2) {
            WRITEW();                         // L2 re-read, overlaps scan
        }
        __syncthreads();
    }
    #undef LOADN
    #undef STEPN
    #undef RENORM16
    #undef WRITEW

    if (t < 64) {
        int jstar = text_len[b] - 1;               // in [63,127]
        float vs = (jstar & 1) ? fin1 : fin0;
        int   vh = fsh;
        vs = __shfl(vs, jstar >> 1);
        vh = __shfl(vh, jstar >> 1);
        if (l == 0) {
            float ms = 0.f;
            #pragma unroll
            for (int k = 0; k < 8; ++k) ms += wsum[k];
            float val = __logf(vs) + (float)vh * LN2F + ms + s_lp00;
            atomicAdd(out0, -(val / (float)Tend) * (1.f / (float)B_));
        }
    }
}

// ---------------------------------------------------------------------------
extern "C" void kernel_launch(void* const* d_in, const int* in_sizes, int n_in,
                              void* d_out, int out_size, void* d_ws, size_t ws_size,
                              hipStream_t stream) {
    const float* mu_logvar = (const float*)d_in[0];
    const float* melspec   = (const float*)d_in[1];
    const int*   text_len  = (const int*)d_in[2];
    const int*   mel_len   = (const int*)d_in[3];

    float* out    = (float*)d_out;      // out[0] = mdn_loss, out[1..] = lp
    float* lp_out = out + 1;
    (void)d_ws; (void)ws_size;          // workspace no longer used

    dim3 g1(TXT_ / IT_, B_);
    lp_kernel<<<g1, MEL_, 0, stream>>>(mu_logvar, melspec, lp_out, out);
    fused_scan<<<B_, 512, 0, stream>>>(lp_out, text_len, mel_len, out);
}

// Round 5
// 154.648 us; speedup vs baseline: 2.0861x; 2.0861x over previous
//
#include <hip/hip_runtime.h>
#include <hip/hip_fp16.h>

#define NEG  (-1e30f)
#define LN2F 0.69314718056f

// Problem dims (fixed by setup_inputs): B=16, TXT=128, MEL=512, NM=80
#define B_   16
#define TXT_ 128
#define MEL_ 512
#define NM_  80
#define IT_  8     // i-rows per lp block

#define CH_   80                  // mel rows per LDS chunk (5 x 16 groups)
#define NCH_  7                   // ceil(512/80); last chunk = 32 rows
#define CHD_  (CH_ * 64)          // dwords per chunk buffer = 5120 (20 KB)

typedef float vf2 __attribute__((ext_vector_type(2)));

// ---------------------------------------------------------------------------
// Kernel 1: log_prob_matrix (proven since R3). Also zeroes out[0].
// ---------------------------------------------------------------------------
__global__ __launch_bounds__(512) void lp_kernel(
    const float* __restrict__ mu_logvar,  // (B, TXT, 2*NM)
    const float* __restrict__ melspec,    // (B, NM, MEL)
    float* __restrict__ lp_out,           // (B, TXT, MEL)  = d_out + 1
    float* __restrict__ out0)             // d_out[0]
{
    const int i0 = blockIdx.x * IT_;
    const int b  = blockIdx.y;
    const int t  = threadIdx.x;

    __shared__ float2 s_wb[IT_][NM_];
    __shared__ float  s_cp[IT_ * NM_];
    __shared__ float  s_cc[IT_];

    for (int u = t; u < IT_ * NM_; u += 512) {   // 640 > 512: strided loop!
        int ii = u / NM_;
        int n  = u - ii * NM_;
        const float* row = mu_logvar + (size_t)(b * TXT_ + i0 + ii) * (2 * NM_);
        float mu = row[n];
        float lv = row[NM_ + n];
        float w  = __expf(-lv);
        s_wb[ii][n] = make_float2(w, -2.f * mu * w);
        s_cp[u]     = mu * mu * w + lv;
    }
    __syncthreads();
    if (t < IT_) {
        float c = 0.f;
        #pragma unroll
        for (int n = 0; n < NM_; ++n) c += s_cp[t * NM_ + n];
        s_cc[t] = c;
    }
    __syncthreads();

    const float* xcol = melspec + (size_t)b * NM_ * MEL_ + t;
    float acc[IT_];
    #pragma unroll
    for (int ii = 0; ii < IT_; ++ii) acc[ii] = 0.f;

    #pragma unroll 4
    for (int n = 0; n < NM_; ++n) {
        float x  = xcol[(size_t)n * MEL_];
        float x2 = x * x;
        #pragma unroll
        for (int ii = 0; ii < IT_; ++ii) {
            float2 wb = s_wb[ii][n];
            acc[ii] = fmaf(wb.x, x2, fmaf(wb.y, x, acc[ii]));
        }
    }

    const size_t rowbase = ((size_t)(b * TXT_ + i0)) * MEL_ + t;
    #pragma unroll
    for (int ii = 0; ii < IT_; ++ii) {
        lp_out[rowbase + (size_t)ii * MEL_] =
            (-0.5f / (float)NM_) * (acc[ii] + s_cc[ii]);
    }

    if (i0 == 0 && b == 0 && t == 0) *out0 = 0.f;
}

// ---------------------------------------------------------------------------
// Kernel 2 (fused wt + scan), static shared (<64 KB), no register stash.
//
// R4 post-mortem: WRITE_SIZE 8.5 MB of scratch spill — full unroll of
// WRITEW hoisted 128 global loads against a 128-VGPR cap (launch_bounds'
// default waves/EU). Fixes here:
//   (a) __launch_bounds__(512, 2): a 512-thread block IS 2 waves/SIMD, so
//       declare exactly that -> register cap rises to 256 VGPR, no spill.
//   (b) WRITEW unroll capped at 8 (16 loads in flight/thread, not 128).
// Everything else (chunk pipeline, swizzle, scan machinery, renorm
// cadence) is the numerics-proven R3/R4 structure.
//
// Pipeline: 3-buffer chunks of CH=80 mel rows (60 KB LDS). Iter c: wave0
// scans chunk c from buf[c%3] while threads owning chunk c+2 exp+pack+
// write buf[(c+2)%3] (L2 re-read of lp, overlapped); one barrier per iter.
// LDS swizzle D(row,p) = row*64 + (p ^ (row&31)): both access patterns
// <=2-way (free). Scan: DPP shr1 + add/mul, exact power-of-2 renorm every
// <=16 steps. fp16 only touches w (<=1/2, 2.4e-4 rel); lp output untouched.
// ---------------------------------------------------------------------------
__device__ __forceinline__ float dpp_shr1_zero(float x) {
    int r = __builtin_amdgcn_update_dpp(
        0, __builtin_bit_cast(int, x), 0x138 /*wave_shr:1*/, 0xf, 0xf, false);
    return __builtin_bit_cast(float, r);
}

#define DPPMAX(M, CTRL, RM)                                               \
    do {                                                                  \
        int _t = __builtin_amdgcn_update_dpp(                             \
            __builtin_bit_cast(int, M), __builtin_bit_cast(int, M),       \
            CTRL, RM, 0xf, false);                                        \
        M = fmaxf(M, __builtin_bit_cast(float, _t));                      \
    } while (0)

__global__ __launch_bounds__(512, 2) void fused_scan(
    const float* __restrict__ lp,          // (B, TXT, MEL) = d_out + 1
    const int* __restrict__ text_len, const int* __restrict__ mel_len,
    float* __restrict__ out0)
{
    __shared__ unsigned int wbuf[3 * CHD_];   // 60 KB
    __shared__ float wsum[8];
    __shared__ float s_lp00;

    const int b = blockIdx.x;
    const int t = threadIdx.x;                // mel column, 0..511
    const int l = t;                          // lane id when in wave 0
    const float* col = lp + (size_t)b * TXT_ * MEL_ + t;

    const int Tend = mel_len[b], TendM1 = Tend - 1;   // Tend in [256,512]

    // ---- Phase A: column max only ---------------------------------------
    float m = NEG;
    #pragma unroll 8
    for (int p = 0; p < TXT_; ++p) m = fmaxf(m, col[(size_t)p * MEL_]);
    const float mu_t = m + LN2F;

    float contrib = (t >= 1 && t <= TendM1) ? mu_t : 0.f;
    #pragma unroll
    for (int off = 32; off; off >>= 1) contrib += __shfl_down(contrib, off);
    if ((t & 63) == 0) wsum[t >> 6] = contrib;
    if (t == 0) s_lp00 = col[0];              // lp[b][0][0]

    const int myc  = t / CH_;                 // this thread's chunk
    const int rloc = t - myc * CH_;
    unsigned int* wb = wbuf + (myc % 3) * CHD_ + rloc * 64;
    const int swz = t & 31;

    #define WRITEW()                                                      \
        do {                                                              \
            _Pragma("unroll 8")                                           \
            for (int p = 0; p < 64; ++p) {                                \
                float f0 = col[(size_t)(2 * p)     * MEL_];               \
                float f1 = col[(size_t)(2 * p + 1) * MEL_];               \
                float e0 = __expf(f0 - mu_t);                             \
                float e1 = __expf(f1 - mu_t);                             \
                wb[p ^ swz] = __builtin_bit_cast(                         \
                    unsigned int, __floats2half2_rn(e0, e1));             \
            }                                                             \
        } while (0)

    if (myc <= 1) WRITEW();                   // chunks 0,1 pre-filled
    __syncthreads();

    // ---- Phase C state -------------------------------------------------
    float s0 = (l == 0) ? 1.f : 0.f;
    float s1 = 0.f;
    float fin0 = 0.f, fin1 = 0.f;
    int   shift_acc = 0, fsh = 0;
    vf2 A[16], Bq[16];

    #define LOADN(ARR, RL0, N)                                            \
        _Pragma("unroll")                                                 \
        for (int j = 0; j < (N); ++j) {                                   \
            int rl = (RL0) + j;                                           \
            unsigned int u_ = bb[rl * 64 + (l ^ ((lo + rl) & 31))];       \
            float2 f_ = __half22float2(__builtin_bit_cast(__half2, u_));  \
            ARR[j].x = f_.x; ARR[j].y = f_.y;                             \
        }

    #define STEPN(ARR, RL0, N)                                            \
        _Pragma("unroll")                                                 \
        for (int j = 0; j < (N); ++j) {                                   \
            int row = lo + (RL0) + j;                                     \
            float nb  = dpp_shr1_zero(s1);                                \
            float ns0 = (s0 + nb) * ARR[j].x;                             \
            float ns1 = (s1 + s0) * ARR[j].y;                             \
            bool hit = (row == TendM1);                                   \
            fin0 = hit ? ns0 : fin0;                                      \
            fin1 = hit ? ns1 : fin1;                                      \
            fsh  = hit ? shift_acc : fsh;                                 \
            s0 = ns0; s1 = ns1;                                           \
        }

    #define RENORM16()                                                    \
        do {                                                              \
            float mm = fmaxf(s0, s1);                                     \
            DPPMAX(mm, 0x111, 0xf);   /* row_shr:1  */                    \
            DPPMAX(mm, 0x112, 0xf);   /* row_shr:2  */                    \
            DPPMAX(mm, 0x114, 0xf);   /* row_shr:4  */                    \
            DPPMAX(mm, 0x118, 0xf);   /* row_shr:8  */                    \
            DPPMAX(mm, 0x142, 0xa);   /* row_bcast:15 -> rows 1,3 */      \
            DPPMAX(mm, 0x143, 0xc);   /* row_bcast:31 -> rows 2,3 */      \
            float M = __builtin_bit_cast(                                 \
                float, __builtin_amdgcn_readlane(                         \
                           __builtin_bit_cast(int, mm), 63));             \
            if (M > 0.f) {                                                \
                int e;                                                    \
                (void)frexpf(M, &e);                                      \
                float sc = ldexpf(1.f, -e);                               \
                s0 *= sc; s1 *= sc;                                       \
                shift_acc += e;                                           \
            }                                                             \
        } while (0)

    for (int c = 0; c < NCH_; ++c) {
        if (t < 64) {
            const unsigned int* bb = wbuf + (c % 3) * CHD_;
            const int lo = c * CH_;
            if (c == 0) {
                LOADN(A, 1, 15); LOADN(Bq, 16, 16);
                STEPN(A, 1, 15);  RENORM16();
                LOADN(A, 32, 16); STEPN(Bq, 16, 16); RENORM16();
                LOADN(Bq, 48, 16); STEPN(A, 32, 16); RENORM16();
                LOADN(A, 64, 16); STEPN(Bq, 48, 16); RENORM16();
                STEPN(A, 64, 16); RENORM16();
            } else if (c < 6) {
                LOADN(A, 0, 16); LOADN(Bq, 16, 16);
                STEPN(A, 0, 16);  RENORM16();
                LOADN(A, 32, 16); STEPN(Bq, 16, 16); RENORM16();
                LOADN(Bq, 48, 16); STEPN(A, 32, 16); RENORM16();
                LOADN(A, 64, 16); STEPN(Bq, 48, 16); RENORM16();
                STEPN(A, 64, 16); RENORM16();
            } else {                          // c == 6: rows 480..511
                LOADN(A, 0, 16); LOADN(Bq, 16, 16);
                STEPN(A, 0, 16);  RENORM16();
                STEPN(Bq, 16, 16); RENORM16();
            }
        } else if (myc == c + 2) {
            WRITEW();                         // L2 re-read, overlaps scan
        }
        __syncthreads();
    }
    #undef LOADN
    #undef STEPN
    #undef RENORM16
    #undef WRITEW

    if (t < 64) {
        int jstar = text_len[b] - 1;               // in [63,127]
        float vs = (jstar & 1) ? fin1 : fin0;
        int   vh = fsh;
        vs = __shfl(vs, jstar >> 1);
        vh = __shfl(vh, jstar >> 1);
        if (l == 0) {
            float ms = 0.f;
            #pragma unroll
            for (int k = 0; k < 8; ++k) ms += wsum[k];
            float val = __logf(vs) + (float)vh * LN2F + ms + s_lp00;
            atomicAdd(out0, -(val / (float)Tend) * (1.f / (float)B_));
        }
    }
}

// ---------------------------------------------------------------------------
extern "C" void kernel_launch(void* const* d_in, const int* in_sizes, int n_in,
                              void* d_out, int out_size, void* d_ws, size_t ws_size,
                              hipStream_t stream) {
    const float* mu_logvar = (const float*)d_in[0];
    const float* melspec   = (const float*)d_in[1];
    const int*   text_len  = (const int*)d_in[2];
    const int*   mel_len   = (const int*)d_in[3];

    float* out    = (float*)d_out;      // out[0] = mdn_loss, out[1..] = lp
    float* lp_out = out + 1;
    (void)d_ws; (void)ws_size;          // workspace no longer used

    dim3 g1(TXT_ / IT_, B_);
    lp_kernel<<<g1, MEL_, 0, stream>>>(mu_logvar, melspec, lp_out, out);
    fused_scan<<<B_, 512, 0, stream>>>(lp_out, text_len, mel_len, out);
}

// Round 6
// 124.393 us; speedup vs baseline: 2.5935x; 1.2432x over previous
//
#include <hip/hip_runtime.h>
#include <hip/hip_fp16.h>

#define NEG  (-1e30f)
#define LN2F 0.69314718056f

// Problem dims (fixed by setup_inputs): B=16, TXT=128, MEL=512, NM=80
#define B_   16
#define TXT_ 128
#define MEL_ 512
#define NM_  80
#define IT_  8     // i-rows per lp block

#define CH_   64                  // mel rows per LDS chunk (4 x 16 groups)
#define CHD_  (CH_ * 64)          // dwords per chunk buffer = 4096 (16 KB)

typedef float vf2 __attribute__((ext_vector_type(2)));

// ---------------------------------------------------------------------------
// Kernel 1: log_prob_matrix (proven since R3). Also zeroes out[0].
// ---------------------------------------------------------------------------
__global__ __launch_bounds__(512) void lp_kernel(
    const float* __restrict__ mu_logvar,  // (B, TXT, 2*NM)
    const float* __restrict__ melspec,    // (B, NM, MEL)
    float* __restrict__ lp_out,           // (B, TXT, MEL)  = d_out + 1
    float* __restrict__ out0)             // d_out[0]
{
    const int i0 = blockIdx.x * IT_;
    const int b  = blockIdx.y;
    const int t  = threadIdx.x;

    __shared__ float2 s_wb[IT_][NM_];
    __shared__ float  s_cp[IT_ * NM_];
    __shared__ float  s_cc[IT_];

    for (int u = t; u < IT_ * NM_; u += 512) {   // 640 > 512: strided loop!
        int ii = u / NM_;
        int n  = u - ii * NM_;
        const float* row = mu_logvar + (size_t)(b * TXT_ + i0 + ii) * (2 * NM_);
        float mu = row[n];
        float lv = row[NM_ + n];
        float w  = __expf(-lv);
        s_wb[ii][n] = make_float2(w, -2.f * mu * w);
        s_cp[u]     = mu * mu * w + lv;
    }
    __syncthreads();
    if (t < IT_) {
        float c = 0.f;
        #pragma unroll
        for (int n = 0; n < NM_; ++n) c += s_cp[t * NM_ + n];
        s_cc[t] = c;
    }
    __syncthreads();

    const float* xcol = melspec + (size_t)b * NM_ * MEL_ + t;
    float acc[IT_];
    #pragma unroll
    for (int ii = 0; ii < IT_; ++ii) acc[ii] = 0.f;

    #pragma unroll 4
    for (int n = 0; n < NM_; ++n) {
        float x  = xcol[(size_t)n * MEL_];
        float x2 = x * x;
        #pragma unroll
        for (int ii = 0; ii < IT_; ++ii) {
            float2 wb = s_wb[ii][n];
            acc[ii] = fmaf(wb.x, x2, fmaf(wb.y, x, acc[ii]));
        }
    }

    const size_t rowbase = ((size_t)(b * TXT_ + i0)) * MEL_ + t;
    #pragma unroll
    for (int ii = 0; ii < IT_; ++ii) {
        lp_out[rowbase + (size_t)ii * MEL_] =
            (-0.5f / (float)NM_) * (acc[ii] + s_cc[ii]);
    }

    if (i0 == 0 && b == 0 && t == 0) *out0 = 0.f;
}

// ---------------------------------------------------------------------------
// Kernel 2 (fused wt + scan). R5 post-mortem: 79 us with ZERO memory traffic
// on warm replays -> internal stall; per-active-CU VALU issue (~11 us) matched
// the instruction count, so the 68 us gap is instruction-stream stall from
// the mega-unrolled 3-variant chunk bodies (tens of KB streamed by a single
// wave against 32 KB L1I at 1-wave occupancy). Fixes:
//   (a) #pragma unroll 1 chunk loop + CH=64 (4 even groups): hot body ~8 KB,
//       permanently L1I-resident. Wave id == chunk id.
//   (b) frexpf/ldexpf -> exact bit-op renorm (no out-param/scratch/call risk):
//       M in [0,1] => be<=127; e = be-126, sc = 2^(126-be) — bit-identical.
//   (c) loop only to lastc = TendM1>>6 (Tend in [256,512] => skip up to 4
//       chunks); columns t > TendM1 write w=0 (clean decay, no inf/NaN).
// Everything else (3-buffer pipeline, XOR swizzle, DPP scan, 16-step renorm
// cadence, fp16-only-on-w) is the numerics-proven structure.
// ---------------------------------------------------------------------------
__device__ __forceinline__ float dpp_shr1_zero(float x) {
    int r = __builtin_amdgcn_update_dpp(
        0, __builtin_bit_cast(int, x), 0x138 /*wave_shr:1*/, 0xf, 0xf, false);
    return __builtin_bit_cast(float, r);
}

#define DPPMAX(M, CTRL, RM)                                               \
    do {                                                                  \
        int _t = __builtin_amdgcn_update_dpp(                             \
            __builtin_bit_cast(int, M), __builtin_bit_cast(int, M),       \
            CTRL, RM, 0xf, false);                                        \
        M = fmaxf(M, __builtin_bit_cast(float, _t));                      \
    } while (0)

__global__ __launch_bounds__(512, 2) void fused_scan(
    const float* __restrict__ lp,          // (B, TXT, MEL) = d_out + 1
    const int* __restrict__ text_len, const int* __restrict__ mel_len,
    float* __restrict__ out0)
{
    __shared__ unsigned int wbuf[3 * CHD_];   // 48 KB
    __shared__ float wsum[8];
    __shared__ float s_lp00;

    const int b = blockIdx.x;
    const int t = threadIdx.x;                // mel column, 0..511
    const int l = t;                          // lane id when in wave 0
    const float* col = lp + (size_t)b * TXT_ * MEL_ + t;

    const int Tend = mel_len[b], TendM1 = Tend - 1;   // Tend in [256,512]
    const int lastc = TendM1 >> 6;            // last chunk index, 3..7
    const bool live = (t <= TendM1);

    // ---- Phase A: column max only ---------------------------------------
    float m = NEG;
    if (live) {
        #pragma unroll 8
        for (int p = 0; p < TXT_; ++p) m = fmaxf(m, col[(size_t)p * MEL_]);
    }
    const float mu_t = m + LN2F;

    float contrib = (t >= 1 && t <= TendM1) ? mu_t : 0.f;
    #pragma unroll
    for (int off = 32; off; off >>= 1) contrib += __shfl_down(contrib, off);
    if ((t & 63) == 0) wsum[t >> 6] = contrib;
    if (t == 0) s_lp00 = col[0];              // lp[b][0][0]

    const int myc  = t >> 6;                  // wave id == chunk id (CH=64)
    const int rloc = t & 63;
    unsigned int* wb = wbuf + (myc % 3) * CHD_ + rloc * 64;
    const int swz = t & 31;

    #define WRITEW()                                                      \
        do {                                                              \
            if (live) {                                                   \
                _Pragma("unroll 8")                                       \
                for (int p = 0; p < 64; ++p) {                            \
                    float f0 = col[(size_t)(2 * p)     * MEL_];           \
                    float f1 = col[(size_t)(2 * p + 1) * MEL_];           \
                    float e0 = __expf(f0 - mu_t);                         \
                    float e1 = __expf(f1 - mu_t);                         \
                    wb[p ^ swz] = __builtin_bit_cast(                     \
                        unsigned int, __floats2half2_rn(e0, e1));         \
                }                                                         \
            } else {                                                      \
                _Pragma("unroll 8")                                       \
                for (int p = 0; p < 64; ++p) wb[p ^ swz] = 0u;            \
            }                                                             \
        } while (0)

    if (myc <= 1) WRITEW();                   // chunks 0,1 pre-filled
    __syncthreads();

    // ---- Phase C state -------------------------------------------------
    float s0 = (l == 0) ? 1.f : 0.f;
    float s1 = 0.f;
    float fin0 = 0.f, fin1 = 0.f;
    int   shift_acc = 0, fsh = 0;
    vf2 A[16], Bq[16];

    #define LOADN(ARR, R0)                                                \
        _Pragma("unroll")                                                 \
        for (int j = 0; j < 16; ++j) {                                    \
            int rl = (R0) + j;                                            \
            unsigned int u_ = bb[(rl << 6) + (l ^ (rl & 31))];            \
            float2 f_ = __half22float2(__builtin_bit_cast(__half2, u_));  \
            ARR[j].x = f_.x; ARR[j].y = f_.y;                             \
        }

    #define STEPN(ARR, R0, J0)                                            \
        _Pragma("unroll")                                                 \
        for (int j = (J0); j < 16; ++j) {                                 \
            int row = lo + (R0) + j;                                      \
            float nb  = dpp_shr1_zero(s1);                                \
            float ns0 = (s0 + nb) * ARR[j].x;                             \
            float ns1 = (s1 + s0) * ARR[j].y;                             \
            bool hit = (row == TendM1);                                   \
            fin0 = hit ? ns0 : fin0;                                      \
            fin1 = hit ? ns1 : fin1;                                      \
            fsh  = hit ? shift_acc : fsh;                                 \
            s0 = ns0; s1 = ns1;                                           \
        }

    // exact power-of-2 renorm, bit-op form (M in [0,1] -> be <= 127)
    #define RENORM16()                                                    \
        do {                                                              \
            float mm = fmaxf(s0, s1);                                     \
            DPPMAX(mm, 0x111, 0xf);   /* row_shr:1  */                    \
            DPPMAX(mm, 0x112, 0xf);   /* row_shr:2  */                    \
            DPPMAX(mm, 0x114, 0xf);   /* row_shr:4  */                    \
            DPPMAX(mm, 0x118, 0xf);   /* row_shr:8  */                    \
            DPPMAX(mm, 0x142, 0xa);   /* row_bcast:15 -> rows 1,3 */      \
            DPPMAX(mm, 0x143, 0xc);   /* row_bcast:31 -> rows 2,3 */      \
            int ib = __builtin_amdgcn_readlane(                           \
                         __builtin_bit_cast(int, mm), 63);                \
            int be = (ib >> 23) & 0xff;                                   \
            if (be > 0) {                                                 \
                float sc = __builtin_bit_cast(float, (253 - be) << 23);   \
                s0 *= sc; s1 *= sc;                                       \
                shift_acc += be - 126;                                    \
            }                                                             \
        } while (0)

    #pragma unroll 1
    for (int c = 0; c <= lastc; ++c) {
        if (t < 64) {
            const unsigned int* bb = wbuf + (c % 3) * CHD_;
            const int lo = c << 6;
            LOADN(A, 0);
            LOADN(Bq, 16);
            if (c == 0) { STEPN(A, 0, 1); } else { STEPN(A, 0, 0); }
            RENORM16();
            LOADN(A, 32);  STEPN(Bq, 16, 0); RENORM16();
            LOADN(Bq, 48); STEPN(A, 32, 0);  RENORM16();
            STEPN(Bq, 48, 0); RENORM16();
        } else if (myc == c + 2 && myc <= lastc) {
            WRITEW();                         // L2 re-read, overlaps scan
        }
        __syncthreads();
    }
    #undef LOADN
    #undef STEPN
    #undef RENORM16
    #undef WRITEW

    if (t < 64) {
        int jstar = text_len[b] - 1;               // in [63,127]
        float vs = (jstar & 1) ? fin1 : fin0;
        int   vh = fsh;
        vs = __shfl(vs, jstar >> 1);
        vh = __shfl(vh, jstar >> 1);
        if (l == 0) {
            float ms = 0.f;
            #pragma unroll
            for (int k = 0; k < 8; ++k) ms += wsum[k];
            float val = __logf(vs) + (float)vh * LN2F + ms + s_lp00;
            atomicAdd(out0, -(val / (float)Tend) * (1.f / (float)B_));
        }
    }
}

// ---------------------------------------------------------------------------
extern "C" void kernel_launch(void* const* d_in, const int* in_sizes, int n_in,
                              void* d_out, int out_size, void* d_ws, size_t ws_size,
                              hipStream_t stream) {
    const float* mu_logvar = (const float*)d_in[0];
    const float* melspec   = (const float*)d_in[1];
    const int*   text_len  = (const int*)d_in[2];
    const int*   mel_len   = (const int*)d_in[3];

    float* out    = (float*)d_out;      // out[0] = mdn_loss, out[1..] = lp
    float* lp_out = out + 1;
    (void)d_ws; (void)ws_size;          // workspace no longer used

    dim3 g1(TXT_ / IT_, B_);
    lp_kernel<<<g1, MEL_, 0, stream>>>(mu_logvar, melspec, lp_out, out);
    fused_scan<<<B_, 512, 0, stream>>>(lp_out, text_len, mel_len, out);
}

// Round 7
// 103.695 us; speedup vs baseline: 3.1111x; 1.1996x over previous
//
#include <hip/hip_runtime.h>
#include <hip/hip_fp16.h>

#define NEG  (-1e30f)
#define LN2F 0.69314718056f

// Problem dims (fixed by setup_inputs): B=16, TXT=128, MEL=512, NM=80
#define B_   16
#define TXT_ 128
#define MEL_ 512
#define NM_  80
#define IT_  8     // i-rows per lp block

typedef float vf2 __attribute__((ext_vector_type(2)));

// ---------------------------------------------------------------------------
// R7 structure: back to the PROVEN 3-kernel decoupled dataflow (R1 = 103.9us
// total; fused variants R3-R6 never beat it — barrier-coupled producer/
// consumer in one block serializes what the 3-kernel pipeline overlaps).
// Improvements over R1:
//  * wp format: fp16 pair-packed. Unit u (u in [0,256)) holds rows 2u+1 and
//    2u+2 of w for a lane's two columns in ONE uint2 -> one 8-B load per 2
//    scan steps. 2 MB total (was 4 MB f32). fp16-on-w proven R3-R6.
//  * musum in a small ws array (atomicAdd), no stash-row hack.
//  * bit-op exact power-of-2 renorm (proven R6), cadence <=16 rows (exact
//    rescale -> cadence realignment is bit-neutral).
// ---------------------------------------------------------------------------

// ---------------------------------------------------------------------------
// Kernel 1: log_prob_matrix (proven since R3). Zeroes out[0] and musum[].
// ---------------------------------------------------------------------------
__global__ __launch_bounds__(512) void lp_kernel(
    const float* __restrict__ mu_logvar,  // (B, TXT, 2*NM)
    const float* __restrict__ melspec,    // (B, NM, MEL)
    float* __restrict__ lp_out,           // (B, TXT, MEL)  = d_out + 1
    float* __restrict__ musum,            // (B) in ws
    float* __restrict__ out0)             // d_out[0]
{
    const int i0 = blockIdx.x * IT_;
    const int b  = blockIdx.y;
    const int t  = threadIdx.x;

    __shared__ float2 s_wb[IT_][NM_];
    __shared__ float  s_cp[IT_ * NM_];
    __shared__ float  s_cc[IT_];

    for (int u = t; u < IT_ * NM_; u += 512) {   // 640 > 512: strided loop!
        int ii = u / NM_;
        int n  = u - ii * NM_;
        const float* row = mu_logvar + (size_t)(b * TXT_ + i0 + ii) * (2 * NM_);
        float mu = row[n];
        float lv = row[NM_ + n];
        float w  = __expf(-lv);
        s_wb[ii][n] = make_float2(w, -2.f * mu * w);
        s_cp[u]     = mu * mu * w + lv;
    }
    __syncthreads();
    if (t < IT_) {
        float c = 0.f;
        #pragma unroll
        for (int n = 0; n < NM_; ++n) c += s_cp[t * NM_ + n];
        s_cc[t] = c;
    }
    __syncthreads();

    const float* xcol = melspec + (size_t)b * NM_ * MEL_ + t;
    float acc[IT_];
    #pragma unroll
    for (int ii = 0; ii < IT_; ++ii) acc[ii] = 0.f;

    #pragma unroll 4
    for (int n = 0; n < NM_; ++n) {
        float x  = xcol[(size_t)n * MEL_];
        float x2 = x * x;
        #pragma unroll
        for (int ii = 0; ii < IT_; ++ii) {
            float2 wb = s_wb[ii][n];
            acc[ii] = fmaf(wb.x, x2, fmaf(wb.y, x, acc[ii]));
        }
    }

    const size_t rowbase = ((size_t)(b * TXT_ + i0)) * MEL_ + t;
    #pragma unroll
    for (int ii = 0; ii < IT_; ++ii) {
        lp_out[rowbase + (size_t)ii * MEL_] =
            (-0.5f / (float)NM_) * (acc[ii] + s_cc[ii]);
    }

    if (i0 == 0 && t == 0) musum[b] = 0.f;
    if (i0 == 0 && b == 0 && t == 0) *out0 = 0.f;
}

// ---------------------------------------------------------------------------
// Kernel 2: shift + exp + transpose + PAIR-PACK to fp16.
//   Tile x covers mel cols t0+1 .. t0+32 (t0 = 32x); col 512 clamps to 511
//   (duplicate row, scan never latches it: TendM1 <= 511).
//   mu_t = max_i lp[b][i][t] (+ln2); w[t][i] = exp(lp - mu_t - ln2) <= 1/2.
//   wp[b][u][l] = uint2{ half2(w[2u+1][2l], w[2u+1][2l+1]),
//                        half2(w[2u+2][2l], w[2u+2][2l+1]) }
//   musum[b] += sum_{t in tile, t<=TendM1} mu_t   (+ lp00 from tile 0)
// ---------------------------------------------------------------------------
__global__ __launch_bounds__(256) void wt_kernel(
    const float* __restrict__ lp,   // (B, TXT, MEL) = d_out + 1
    const int* __restrict__ mel_len,
    float* __restrict__ musum,      // (B) in ws
    uint2* __restrict__ wp)         // (B, 256, 64) in ws
{
    __shared__ float tileT[32][TXT_ + 1];   // [c][i], pad breaks conflicts
    __shared__ float pmax[32][8];
    __shared__ float psum[32];

    const int x   = blockIdx.x;        // 0..15
    const int t0  = x * 32;            // tile = mel cols t0+1 .. t0+32
    const int b   = blockIdx.y;
    const int tid = threadIdx.x;       // 0..255

    const float* src = lp + (size_t)b * TXT_ * MEL_;
    for (int u = tid; u < TXT_ * 32; u += 256) {
        int i = u >> 5, c = u & 31;
        int tg = min(t0 + 1 + c, MEL_ - 1);
        tileT[c][i] = src[(size_t)i * MEL_ + tg];
    }
    __syncthreads();

    {   // 8-way partial max over i per local col
        int cc = tid >> 3, g = tid & 7;
        float m = NEG;
        #pragma unroll
        for (int k = 0; k < 16; ++k) m = fmaxf(m, tileT[cc][g * 16 + k]);
        pmax[cc][g] = m;
    }
    __syncthreads();
    if (tid < 32) {
        float m = pmax[tid][0];
        #pragma unroll
        for (int g = 1; g < 8; ++g) m = fmaxf(m, pmax[tid][g]);
        float mu = m + LN2F;
        pmax[tid][0] = mu;                         // mu_t (+ln2)
        int tg = t0 + 1 + tid;                     // UNclamped for the gate
        int TendM1 = mel_len[b] - 1;
        psum[tid] = (tg <= TendM1) ? mu : 0.f;
    }
    __syncthreads();

    uint2* dst = wp + ((size_t)b * 256 + (t0 >> 1)) * 64;
    for (int u = tid; u < 16 * 64; u += 256) {
        int ul = u >> 6, l = u & 63;               // local unit, lane-col
        float m0 = pmax[2 * ul][0];
        float m1 = pmax[2 * ul + 1][0];
        float a0 = __expf(tileT[2 * ul][2 * l]     - m0);
        float a1 = __expf(tileT[2 * ul][2 * l + 1] - m0);
        float b0 = __expf(tileT[2 * ul + 1][2 * l]     - m1);
        float b1 = __expf(tileT[2 * ul + 1][2 * l + 1] - m1);
        uint2 q;
        q.x = __builtin_bit_cast(unsigned int, __floats2half2_rn(a0, a1));
        q.y = __builtin_bit_cast(unsigned int, __floats2half2_rn(b0, b1));
        dst[(size_t)ul * 64 + l] = q;
    }

    if (tid == 0) {
        float s = 0.f;
        #pragma unroll
        for (int k = 0; k < 32; ++k) s += psum[k];
        if (x == 0) s += src[0];                   // + lp[b][0][0]
        atomicAdd(&musum[b], s);
    }
}

// ---------------------------------------------------------------------------
// Kernel 3: linear-domain scan (R10 machinery + R9 numerics).
//   s[t][j] = (s[t-1][j] + s[t-1][j-1]) * w[t][j],  w <= 1/2 (pre-exp'd).
// Lane l owns cols j0=2l, j1=2l+1. One uint2 load per UNIT (2 steps).
// 24 units (48 rows) in flight; s_waitcnt vmcnt(20) per 4-unit group
// (loads complete in order; lead ~5 groups ~1000+ cy covers L3 latency).
// Exact bit-op power-of-2 renorm every 16 rows. fin latched at TendM1;
// overshoot rows are valid/clamped data, harmless.
// ---------------------------------------------------------------------------
__device__ __forceinline__ float dpp_shr1_zero(float x) {
    int r = __builtin_amdgcn_update_dpp(
        0, __builtin_bit_cast(int, x), 0x138 /*wave_shr:1*/, 0xf, 0xf, false);
    return __builtin_bit_cast(float, r);
}

#define DPPMAX(M, CTRL, RM)                                               \
    do {                                                                  \
        int _t = __builtin_amdgcn_update_dpp(                             \
            __builtin_bit_cast(int, M), __builtin_bit_cast(int, M),       \
            CTRL, RM, 0xf, false);                                        \
        M = fmaxf(M, __builtin_bit_cast(float, _t));                      \
    } while (0)

#define GLOAD2(DST, PTR) \
    asm volatile("global_load_dwordx2 %0, %1, off" : "=v"(DST) : "v"(PTR))
#define VWAIT20(A,B,C,D2) \
    asm volatile("s_waitcnt vmcnt(20)" : "+v"(A), "+v"(B), "+v"(C), "+v"(D2))

__global__ __launch_bounds__(64) void scan_kernel(
    const uint2* __restrict__ wp,          // (B, 256, 64) in ws
    const float* __restrict__ musum,       // (B) in ws
    const int* __restrict__ text_len, const int* __restrict__ mel_len,
    float* __restrict__ out0)
{
    const int b = blockIdx.x;
    const int l = threadIdx.x;
    const uint2* pb = wp + (size_t)b * 256 * 64 + l;
    const int Tend = mel_len[b], TendM1 = Tend - 1;   // Tend in [256,512]

    float s0 = (l == 0) ? 1.f : 0.f;   // s[t][j0]
    float s1 = 0.f;                    // s[t][j1]
    float fin0 = 0.f, fin1 = 0.f;
    int   shift_acc = 0, fsh = 0;
    int   t_cur = 1;
    int   u_pf  = 24;                  // next refill unit

    vf2 q0,q1,q2,q3,q4,q5,q6,q7,q8,q9,q10,q11,
        q12,q13,q14,q15,q16,q17,q18,q19,q20,q21,q22,q23;
    {
        #define INIT(Q, U) do { const uint2* p_ = pb + (size_t)(U) * 64; \
                                GLOAD2(Q, p_); } while (0)
        INIT(q0,0);   INIT(q1,1);   INIT(q2,2);   INIT(q3,3);
        INIT(q4,4);   INIT(q5,5);   INIT(q6,6);   INIT(q7,7);
        INIT(q8,8);   INIT(q9,9);   INIT(q10,10); INIT(q11,11);
        INIT(q12,12); INIT(q13,13); INIT(q14,14); INIT(q15,15);
        INIT(q16,16); INIT(q17,17); INIT(q18,18); INIT(q19,19);
        INIT(q20,20); INIT(q21,21); INIT(q22,22); INIT(q23,23);
        #undef INIT
    }

    #define STEP1(WX, WY)                                    \
        do {                                                 \
            float nb  = dpp_shr1_zero(s1);                   \
            float ns0 = (s0 + nb) * (WX);                    \
            float ns1 = (s1 + s0) * (WY);                    \
            bool hit = (t_cur == TendM1);                    \
            fin0 = hit ? ns0 : fin0;                         \
            fin1 = hit ? ns1 : fin1;                         \
            fsh  = hit ? shift_acc : fsh;                    \
            s0 = ns0; s1 = ns1; ++t_cur;                     \
        } while (0)

    #define STEP2(Q)                                                      \
        do {                                                              \
            float2 fa = __half22float2(__builtin_bit_cast(__half2, (Q).x)); \
            float2 fb = __half22float2(__builtin_bit_cast(__half2, (Q).y)); \
            STEP1(fa.x, fa.y);                                            \
            STEP1(fb.x, fb.y);                                            \
        } while (0)

    #define REFILL(Q)                                        \
        do {                                                 \
            int ru = min(u_pf, 255);                         \
            const uint2* p_ = pb + (size_t)ru * 64;          \
            GLOAD2(Q, p_);                                   \
            ++u_pf;                                          \
        } while (0)

    #define GROUP(QA,QB,QC,QD)                               \
        do {                                                 \
            VWAIT20(QA,QB,QC,QD);                            \
            STEP2(QA); STEP2(QB); STEP2(QC); STEP2(QD);      \
            REFILL(QA); REFILL(QB); REFILL(QC); REFILL(QD);  \
        } while (0)

    // exact power-of-2 renorm, bit-op form (M in [0,1] -> be <= 127)
    #define RENORM16()                                                    \
        do {                                                              \
            float mm = fmaxf(s0, s1);                                     \
            DPPMAX(mm, 0x111, 0xf);   /* row_shr:1  */                    \
            DPPMAX(mm, 0x112, 0xf);   /* row_shr:2  */                    \
            DPPMAX(mm, 0x114, 0xf);   /* row_shr:4  */                    \
            DPPMAX(mm, 0x118, 0xf);   /* row_shr:8  */                    \
            DPPMAX(mm, 0x142, 0xa);   /* row_bcast:15 -> rows 1,3 */      \
            DPPMAX(mm, 0x143, 0xc);   /* row_bcast:31 -> rows 2,3 */      \
            int ib = __builtin_amdgcn_readlane(                           \
                         __builtin_bit_cast(int, mm), 63);                \
            int be = (ib >> 23) & 0xff;                                   \
            if (be > 0) {                                                 \
                float sc = __builtin_bit_cast(float, (253 - be) << 23);   \
                s0 *= sc; s1 *= sc;                                       \
                shift_acc += be - 126;                                    \
            }                                                             \
        } while (0)

    // G groups of 4 units (8 rows); body = 6 groups (48 rows, 3 renorms).
    // Overshoot rows (clamped unit 255) are harmless: fin already latched,
    // renorm skips on M==0.
    const int G = (TendM1 + 7) >> 3;           // 32..64
    #pragma unroll 1
    for (int gg = 0; gg < G; gg += 6) {
        GROUP(q0,q1,q2,q3);     GROUP(q4,q5,q6,q7);     RENORM16();
        GROUP(q8,q9,q10,q11);   GROUP(q12,q13,q14,q15); RENORM16();
        GROUP(q16,q17,q18,q19); GROUP(q20,q21,q22,q23); RENORM16();
    }
    #undef STEP1
    #undef STEP2
    #undef REFILL
    #undef GROUP
    #undef RENORM16

    int jstar = text_len[b] - 1;                   // in [63,127]
    float vs = (jstar & 1) ? fin1 : fin0;
    int   vh = fsh;
    vs = __shfl(vs, jstar >> 1);
    vh = __shfl(vh, jstar >> 1);
    if (l == 0) {
        float val = __logf(vs) + (float)vh * LN2F + musum[b];
        atomicAdd(out0, -(val / (float)Tend) * (1.f / (float)B_));
    }
}

// ---------------------------------------------------------------------------
extern "C" void kernel_launch(void* const* d_in, const int* in_sizes, int n_in,
                              void* d_out, int out_size, void* d_ws, size_t ws_size,
                              hipStream_t stream) {
    const float* mu_logvar = (const float*)d_in[0];
    const float* melspec   = (const float*)d_in[1];
    const int*   text_len  = (const int*)d_in[2];
    const int*   mel_len   = (const int*)d_in[3];

    float* out    = (float*)d_out;      // out[0] = mdn_loss, out[1..] = lp
    float* lp_out = out + 1;
    float* musum  = (float*)d_ws;       // 16 floats
    uint2* wp     = (uint2*)((char*)d_ws + 256);   // 2 MB packed weights

    dim3 g1(TXT_ / IT_, B_);
    lp_kernel<<<g1, MEL_, 0, stream>>>(mu_logvar, melspec, lp_out, musum, out);
    dim3 g2(MEL_ / 32, B_);
    wt_kernel<<<g2, 256, 0, stream>>>(lp_out, mel_len, musum, wp);
    scan_kernel<<<B_, 64, 0, stream>>>(wp, musum, text_len, mel_len, out);
}

// Round 8
// 103.144 us; speedup vs baseline: 3.1277x; 1.0053x over previous
//
#include <hip/hip_runtime.h>
#include <hip/hip_fp16.h>

#define NEG  (-1e30f)
#define LN2F 0.69314718056f

// Problem dims (fixed by setup_inputs): B=16, TXT=128, MEL=512, NM=80
#define B_   16
#define TXT_ 128
#define MEL_ 512
#define NM_  80
#define IT_  8     // i-rows per lp block

typedef float vf2 __attribute__((ext_vector_type(2)));

// ---------------------------------------------------------------------------
// R8: R7 structure frozen (proven best: 103.7us). Single change: lp_kernel's
// coefficient reads packed float2->float4, halving broadcast ds_read ops
// (640 b64 -> 320 b128 per thread-loop). Broadcast LDS reads are ISSUE-bound
// (same-address broadcast reads one bank, not 512B of bank traffic), so
// halving the op count halves the DS-pipe time, which was the longer pole
// (5120 ops/block vs ~5.4k cy VALU at 2 waves/SIMD).
// ---------------------------------------------------------------------------

// ---------------------------------------------------------------------------
// Kernel 1: log_prob_matrix. Zeroes out[0] and musum[].
// ---------------------------------------------------------------------------
__global__ __launch_bounds__(512) void lp_kernel(
    const float* __restrict__ mu_logvar,  // (B, TXT, 2*NM)
    const float* __restrict__ melspec,    // (B, NM, MEL)
    float* __restrict__ lp_out,           // (B, TXT, MEL)  = d_out + 1
    float* __restrict__ musum,            // (B) in ws
    float* __restrict__ out0)             // d_out[0]
{
    const int i0 = blockIdx.x * IT_;
    const int b  = blockIdx.y;
    const int t  = threadIdx.x;

    __shared__ float4 s_w4[IT_][NM_ / 2];   // (w,b) pairs for n=2k,2k+1
    __shared__ float  s_cp[IT_ * NM_];
    __shared__ float  s_cc[IT_];

    for (int u = t; u < IT_ * NM_; u += 512) {   // 640 > 512: strided loop!
        int ii = u / NM_;
        int n  = u - ii * NM_;
        const float* row = mu_logvar + (size_t)(b * TXT_ + i0 + ii) * (2 * NM_);
        float mu = row[n];
        float lv = row[NM_ + n];
        float w  = __expf(-lv);
        float2* half_ = reinterpret_cast<float2*>(&s_w4[ii][n >> 1]);
        half_[n & 1] = make_float2(w, -2.f * mu * w);
        s_cp[u]      = mu * mu * w + lv;
    }
    __syncthreads();
    if (t < IT_) {
        float c = 0.f;
        #pragma unroll
        for (int n = 0; n < NM_; ++n) c += s_cp[t * NM_ + n];
        s_cc[t] = c;
    }
    __syncthreads();

    const float* xcol = melspec + (size_t)b * NM_ * MEL_ + t;
    float acc[IT_];
    #pragma unroll
    for (int ii = 0; ii < IT_; ++ii) acc[ii] = 0.f;

    #pragma unroll 2
    for (int n2 = 0; n2 < NM_ / 2; ++n2) {
        float x0  = xcol[(size_t)(2 * n2)     * MEL_];
        float x1  = xcol[(size_t)(2 * n2 + 1) * MEL_];
        float x0s = x0 * x0;
        float x1s = x1 * x1;
        #pragma unroll
        for (int ii = 0; ii < IT_; ++ii) {
            float4 wb = s_w4[ii][n2];       // one ds_read_b128, broadcast
            acc[ii] = fmaf(wb.x, x0s, fmaf(wb.y, x0, acc[ii]));
            acc[ii] = fmaf(wb.z, x1s, fmaf(wb.w, x1, acc[ii]));
        }
    }

    const size_t rowbase = ((size_t)(b * TXT_ + i0)) * MEL_ + t;
    #pragma unroll
    for (int ii = 0; ii < IT_; ++ii) {
        lp_out[rowbase + (size_t)ii * MEL_] =
            (-0.5f / (float)NM_) * (acc[ii] + s_cc[ii]);
    }

    if (i0 == 0 && t == 0) musum[b] = 0.f;
    if (i0 == 0 && b == 0 && t == 0) *out0 = 0.f;
}

// ---------------------------------------------------------------------------
// Kernel 2: shift + exp + transpose + PAIR-PACK to fp16 (R7-proven).
//   Tile x covers mel cols t0+1 .. t0+32 (t0 = 32x); col 512 clamps to 511
//   (duplicate row, scan never latches it: TendM1 <= 511).
//   mu_t = max_i lp[b][i][t] (+ln2); w[t][i] = exp(lp - mu_t - ln2) <= 1/2.
//   wp[b][u][l] = uint2{ half2(w[2u+1][2l], w[2u+1][2l+1]),
//                        half2(w[2u+2][2l], w[2u+2][2l+1]) }
//   musum[b] += sum_{t in tile, t<=TendM1} mu_t   (+ lp00 from tile 0)
// ---------------------------------------------------------------------------
__global__ __launch_bounds__(256) void wt_kernel(
    const float* __restrict__ lp,   // (B, TXT, MEL) = d_out + 1
    const int* __restrict__ mel_len,
    float* __restrict__ musum,      // (B) in ws
    uint2* __restrict__ wp)         // (B, 256, 64) in ws
{
    __shared__ float tileT[32][TXT_ + 1];   // [c][i], pad breaks conflicts
    __shared__ float pmax[32][8];
    __shared__ float psum[32];

    const int x   = blockIdx.x;        // 0..15
    const int t0  = x * 32;            // tile = mel cols t0+1 .. t0+32
    const int b   = blockIdx.y;
    const int tid = threadIdx.x;       // 0..255

    const float* src = lp + (size_t)b * TXT_ * MEL_;
    for (int u = tid; u < TXT_ * 32; u += 256) {
        int i = u >> 5, c = u & 31;
        int tg = min(t0 + 1 + c, MEL_ - 1);
        tileT[c][i] = src[(size_t)i * MEL_ + tg];
    }
    __syncthreads();

    {   // 8-way partial max over i per local col
        int cc = tid >> 3, g = tid & 7;
        float m = NEG;
        #pragma unroll
        for (int k = 0; k < 16; ++k) m = fmaxf(m, tileT[cc][g * 16 + k]);
        pmax[cc][g] = m;
    }
    __syncthreads();
    if (tid < 32) {
        float m = pmax[tid][0];
        #pragma unroll
        for (int g = 1; g < 8; ++g) m = fmaxf(m, pmax[tid][g]);
        float mu = m + LN2F;
        pmax[tid][0] = mu;                         // mu_t (+ln2)
        int tg = t0 + 1 + tid;                     // UNclamped for the gate
        int TendM1 = mel_len[b] - 1;
        psum[tid] = (tg <= TendM1) ? mu : 0.f;
    }
    __syncthreads();

    uint2* dst = wp + ((size_t)b * 256 + (t0 >> 1)) * 64;
    for (int u = tid; u < 16 * 64; u += 256) {
        int ul = u >> 6, l = u & 63;               // local unit, lane-col
        float m0 = pmax[2 * ul][0];
        float m1 = pmax[2 * ul + 1][0];
        float a0 = __expf(tileT[2 * ul][2 * l]     - m0);
        float a1 = __expf(tileT[2 * ul][2 * l + 1] - m0);
        float b0 = __expf(tileT[2 * ul + 1][2 * l]     - m1);
        float b1 = __expf(tileT[2 * ul + 1][2 * l + 1] - m1);
        uint2 q;
        q.x = __builtin_bit_cast(unsigned int, __floats2half2_rn(a0, a1));
        q.y = __builtin_bit_cast(unsigned int, __floats2half2_rn(b0, b1));
        dst[(size_t)ul * 64 + l] = q;
    }

    if (tid == 0) {
        float s = 0.f;
        #pragma unroll
        for (int k = 0; k < 32; ++k) s += psum[k];
        if (x == 0) s += src[0];                   // + lp[b][0][0]
        atomicAdd(&musum[b], s);
    }
}

// ---------------------------------------------------------------------------
// Kernel 3: linear-domain scan (R7-proven, frozen).
//   s[t][j] = (s[t-1][j] + s[t-1][j-1]) * w[t][j],  w <= 1/2 (pre-exp'd).
// Lane l owns cols j0=2l, j1=2l+1. One uint2 load per UNIT (2 steps).
// 24 units (48 rows) in flight; s_waitcnt vmcnt(20) per 4-unit group.
// Exact bit-op power-of-2 renorm every 16 rows. fin latched at TendM1.
// ---------------------------------------------------------------------------
__device__ __forceinline__ float dpp_shr1_zero(float x) {
    int r = __builtin_amdgcn_update_dpp(
        0, __builtin_bit_cast(int, x), 0x138 /*wave_shr:1*/, 0xf, 0xf, false);
    return __builtin_bit_cast(float, r);
}

#define DPPMAX(M, CTRL, RM)                                               \
    do {                                                                  \
        int _t = __builtin_amdgcn_update_dpp(                             \
            __builtin_bit_cast(int, M), __builtin_bit_cast(int, M),       \
            CTRL, RM, 0xf, false);                                        \
        M = fmaxf(M, __builtin_bit_cast(float, _t));                      \
    } while (0)

#define GLOAD2(DST, PTR) \
    asm volatile("global_load_dwordx2 %0, %1, off" : "=v"(DST) : "v"(PTR))
#define VWAIT20(A,B,C,D2) \
    asm volatile("s_waitcnt vmcnt(20)" : "+v"(A), "+v"(B), "+v"(C), "+v"(D2))

__global__ __launch_bounds__(64) void scan_kernel(
    const uint2* __restrict__ wp,          // (B, 256, 64) in ws
    const float* __restrict__ musum,       // (B) in ws
    const int* __restrict__ text_len, const int* __restrict__ mel_len,
    float* __restrict__ out0)
{
    const int b = blockIdx.x;
    const int l = threadIdx.x;
    const uint2* pb = wp + (size_t)b * 256 * 64 + l;
    const int Tend = mel_len[b], TendM1 = Tend - 1;   // Tend in [256,512]

    float s0 = (l == 0) ? 1.f : 0.f;   // s[t][j0]
    float s1 = 0.f;                    // s[t][j1]
    float fin0 = 0.f, fin1 = 0.f;
    int   shift_acc = 0, fsh = 0;
    int   t_cur = 1;
    int   u_pf  = 24;                  // next refill unit

    vf2 q0,q1,q2,q3,q4,q5,q6,q7,q8,q9,q10,q11,
        q12,q13,q14,q15,q16,q17,q18,q19,q20,q21,q22,q23;
    {
        #define INIT(Q, U) do { const uint2* p_ = pb + (size_t)(U) * 64; \
                                GLOAD2(Q, p_); } while (0)
        INIT(q0,0);   INIT(q1,1);   INIT(q2,2);   INIT(q3,3);
        INIT(q4,4);   INIT(q5,5);   INIT(q6,6);   INIT(q7,7);
        INIT(q8,8);   INIT(q9,9);   INIT(q10,10); INIT(q11,11);
        INIT(q12,12); INIT(q13,13); INIT(q14,14); INIT(q15,15);
        INIT(q16,16); INIT(q17,17); INIT(q18,18); INIT(q19,19);
        INIT(q20,20); INIT(q21,21); INIT(q22,22); INIT(q23,23);
        #undef INIT
    }

    #define STEP1(WX, WY)                                    \
        do {                                                 \
            float nb  = dpp_shr1_zero(s1);                   \
            float ns0 = (s0 + nb) * (WX);                    \
            float ns1 = (s1 + s0) * (WY);                    \
            bool hit = (t_cur == TendM1);                    \
            fin0 = hit ? ns0 : fin0;                         \
            fin1 = hit ? ns1 : fin1;                         \
            fsh  = hit ? shift_acc : fsh;                    \
            s0 = ns0; s1 = ns1; ++t_cur;                     \
        } while (0)

    #define STEP2(Q)                                                      \
        do {                                                              \
            float2 fa = __half22float2(__builtin_bit_cast(__half2, (Q).x)); \
            float2 fb = __half22float2(__builtin_bit_cast(__half2, (Q).y)); \
            STEP1(fa.x, fa.y);                                            \
            STEP1(fb.x, fb.y);                                            \
        } while (0)

    #define REFILL(Q)                                        \
        do {                                                 \
            int ru = min(u_pf, 255);                         \
            const uint2* p_ = pb + (size_t)ru * 64;          \
            GLOAD2(Q, p_);                                   \
            ++u_pf;                                          \
        } while (0)

    #define GROUP(QA,QB,QC,QD)                               \
        do {                                                 \
            VWAIT20(QA,QB,QC,QD);                            \
            STEP2(QA); STEP2(QB); STEP2(QC); STEP2(QD);      \
            REFILL(QA); REFILL(QB); REFILL(QC); REFILL(QD);  \
        } while (0)

    // exact power-of-2 renorm, bit-op form (M in [0,1] -> be <= 127)
    #define RENORM16()                                                    \
        do {                                                              \
            float mm = fmaxf(s0, s1);                                     \
            DPPMAX(mm, 0x111, 0xf);   /* row_shr:1  */                    \
            DPPMAX(mm, 0x112, 0xf);   /* row_shr:2  */                    \
            DPPMAX(mm, 0x114, 0xf);   /* row_shr:4  */                    \
            DPPMAX(mm, 0x118, 0xf);   /* row_shr:8  */                    \
            DPPMAX(mm, 0x142, 0xa);   /* row_bcast:15 -> rows 1,3 */      \
            DPPMAX(mm, 0x143, 0xc);   /* row_bcast:31 -> rows 2,3 */      \
            int ib = __builtin_amdgcn_readlane(                           \
                         __builtin_bit_cast(int, mm), 63);                \
            int be = (ib >> 23) & 0xff;                                   \
            if (be > 0) {                                                 \
                float sc = __builtin_bit_cast(float, (253 - be) << 23);   \
                s0 *= sc; s1 *= sc;                                       \
                shift_acc += be - 126;                                    \
            }                                                             \
        } while (0)

    // G groups of 4 units (8 rows); body = 6 groups (48 rows, 3 renorms).
    // Overshoot rows (clamped unit 255) are harmless: fin already latched,
    // renorm skips on M==0.
    const int G = (TendM1 + 7) >> 3;           // 32..64
    #pragma unroll 1
    for (int gg = 0; gg < G; gg += 6) {
        GROUP(q0,q1,q2,q3);     GROUP(q4,q5,q6,q7);     RENORM16();
        GROUP(q8,q9,q10,q11);   GROUP(q12,q13,q14,q15); RENORM16();
        GROUP(q16,q17,q18,q19); GROUP(q20,q21,q22,q23); RENORM16();
    }
    #undef STEP1
    #undef STEP2
    #undef REFILL
    #undef GROUP
    #undef RENORM16

    int jstar = text_len[b] - 1;                   // in [63,127]
    float vs = (jstar & 1) ? fin1 : fin0;
    int   vh = fsh;
    vs = __shfl(vs, jstar >> 1);
    vh = __shfl(vh, jstar >> 1);
    if (l == 0) {
        float val = __logf(vs) + (float)vh * LN2F + musum[b];
        atomicAdd(out0, -(val / (float)Tend) * (1.f / (float)B_));
    }
}

// ---------------------------------------------------------------------------
extern "C" void kernel_launch(void* const* d_in, const int* in_sizes, int n_in,
                              void* d_out, int out_size, void* d_ws, size_t ws_size,
                              hipStream_t stream) {
    const float* mu_logvar = (const float*)d_in[0];
    const float* melspec   = (const float*)d_in[1];
    const int*   text_len  = (const int*)d_in[2];
    const int*   mel_len   = (const int*)d_in[3];

    float* out    = (float*)d_out;      // out[0] = mdn_loss, out[1..] = lp
    float* lp_out = out + 1;
    float* musum  = (float*)d_ws;       // 16 floats
    uint2* wp     = (uint2*)((char*)d_ws + 256);   // 2 MB packed weights

    dim3 g1(TXT_ / IT_, B_);
    lp_kernel<<<g1, MEL_, 0, stream>>>(mu_logvar, melspec, lp_out, musum, out);
    dim3 g2(MEL_ / 32, B_);
    wt_kernel<<<g2, 256, 0, stream>>>(lp_out, mel_len, musum, wp);
    scan_kernel<<<B_, 64, 0, stream>>>(wp, musum, text_len, mel_len, out);
}